// Round 6
// baseline (460.810 us; speedup 1.0000x reference)
//
#include <hip/hip_runtime.h>

typedef _Float16 f16;
typedef __attribute__((ext_vector_type(2))) _Float16 f16x2;
typedef __attribute__((ext_vector_type(2))) __fp16   hf16x2;  // cvt_pkrtz native return
typedef __attribute__((ext_vector_type(4))) _Float16 f16x4;
typedef __attribute__((ext_vector_type(8))) _Float16 f16x8;
typedef __attribute__((ext_vector_type(4))) float    f32x4;

#define D_MODEL 1024
#define HEADS   16
#define DH      64
#define SEQ     2048
#define BATCH   4
#define SSCALE  0.1803368801111204f   // 1/sqrt(64) * log2(e)

// async 16B global->LDS; lds dst is wave-uniform base + lane*16
__device__ __forceinline__ void gload_lds16(const void* g, void* lds) {
  __builtin_amdgcn_global_load_lds(
      (const __attribute__((address_space(1))) unsigned int*)g,
      (__attribute__((address_space(3))) unsigned int*)lds, 16, 0, 0);
}

// ---------------- prep: transpose W only (x-cast fused into qkv) ----------------
__global__ __launch_bounds__(256) void prep_kernel(const float* __restrict__ Wq,
                                                   const float* __restrict__ Wk,
                                                   const float* __restrict__ Wv,
                                                   f16* __restrict__ wt) {
  int bid = blockIdx.x;                        // W [K][N] fp32 -> Wt [N][K] f16
  int z = bid >> 8, rem = bid & 255;
  const float* W = z == 0 ? Wq : (z == 1 ? Wk : Wv);
  f16* out = wt + (size_t)z * D_MODEL * D_MODEL;
  __shared__ float tile[64][65];
  int n0 = (rem & 15) * 64, k0 = (rem >> 4) * 64;
  int tx = threadIdx.x & 63, ty = threadIdx.x >> 6;
#pragma unroll
  for (int r = 0; r < 16; ++r)
    tile[ty * 16 + r][tx] = W[(size_t)(k0 + ty * 16 + r) * D_MODEL + n0 + tx];
  __syncthreads();
#pragma unroll
  for (int r = 0; r < 16; ++r)
    out[(size_t)(n0 + ty * 16 + r) * D_MODEL + k0 + tx] = (f16)tile[tx][ty * 16 + r];
}

// ---------------- QKV projection GEMM ----------------
// 128x128 tile, BK=32, ring-3 LDS. XCD-locality remap (r4: 69.5us measured).
// NEW: A-operand staged directly from f32 x (kills the prep x-cast pass):
// per tile, 4x float4 reg-loads -> 8x v_cvt_f16_f32 (RTE, bit-identical to
// the old prep cast) -> ds_write_b128 to the SAME swizzled LDS bytes.
// Counting (verified): issue/iter i = [B(i+2) 2 gload_lds, A(i+2) 4 loads];
// mid vmcnt(6) retires through A(i+1) -> write it; top needs only lgkmcnt(0)
// +barrier (B(i) retired by iter i-1's vmcnt(6); WAR separated by 2 barriers).
__global__ __launch_bounds__(256, 3) void qkv_gemm_kernel(
    const float* __restrict__ x, const f16* __restrict__ wt_all,
    const float* __restrict__ bq, const float* __restrict__ bk, const float* __restrict__ bv,
    f16* __restrict__ qout, f16* __restrict__ kout, f16* __restrict__ vtout) {
  const int bid = blockIdx.x;
  const int j = bid & 7, t = bid >> 3;
  const int by = j * 8 + (t & 7);            // m-block: contiguous band per XCD
  const int bx = (t >> 3) & 7;               // n-block
  const int z  = t >> 6;                     // q/k/v
  const f16* wt = wt_all + (size_t)z * D_MODEL * D_MODEL;
  const float* bias = z == 0 ? bq : (z == 1 ? bk : bv);
  const int n0 = bx * 128, m0 = by * 128;

  __shared__ f16 As[3][128 * 32];   // 8KB per buffer, ring-3
  __shared__ f16 Bs[3][128 * 32];   // 48KB total -> still 3 blocks/CU

  const int tid = threadIdx.x;
  const int lane = tid & 63, w = tid >> 6;
  const int quad = lane >> 4, l15 = lane & 15;
  const int wm = w & 1, wn = w >> 1;

  const int pce = (quad ^ ((l15 >> 1) & 3)) * 8;
  const int aoff = wm * 2048 + l15 * 32 + pce;
  const int boff = wn * 2048 + l15 * 32 + pce;

  int srow[2], scl[2];
#pragma unroll
  for (int c = 0; c < 2; ++c) {
    int slot = (w * 2 + c) * 64 + lane;
    srow[c] = slot >> 2;
    scl[c] = (slot & 3) ^ ((srow[c] >> 1) & 3);
  }

  f32x4 acc[4][4];
#pragma unroll
  for (int i = 0; i < 4; ++i)
#pragma unroll
    for (int jj = 0; jj < 4; ++jj) acc[i][jj] = (f32x4){0.f, 0.f, 0.f, 0.f};

  float4 pA[2][4];                  // A reg double-buffer: parity = tile&1

  // prologue: issue B(0),A(0),B(1),A(1); vmcnt(6) retires B0+A0; write A(0)
#pragma unroll
  for (int tt = 0; tt < 2; ++tt) {
#pragma unroll
    for (int c = 0; c < 2; ++c)
      gload_lds16(wt + (size_t)(n0 + srow[c]) * D_MODEL + tt * 32 + scl[c] * 8, &Bs[tt][(w * 2 + c) * 512]);
#pragma unroll
    for (int c = 0; c < 2; ++c) {
      const float* xrow = x + (size_t)(m0 + srow[c]) * D_MODEL + tt * 32 + scl[c] * 8;
      pA[tt][c * 2 + 0] = ((const float4*)xrow)[0];
      pA[tt][c * 2 + 1] = ((const float4*)xrow)[1];
    }
  }
  asm volatile("s_waitcnt vmcnt(6)" ::: "memory");
#pragma unroll
  for (int c = 0; c < 2; ++c) {
    f16x8 hv;
    const float4 a = pA[0][c * 2], b2 = pA[0][c * 2 + 1];
    hv[0] = (f16)a.x;  hv[1] = (f16)a.y;  hv[2] = (f16)a.z;  hv[3] = (f16)a.w;
    hv[4] = (f16)b2.x; hv[5] = (f16)b2.y; hv[6] = (f16)b2.z; hv[7] = (f16)b2.w;
    *(f16x8*)(&As[0][(w * 2 + c) * 512 + lane * 8]) = hv;
  }

  f16x8 aP[4], bP[4];
  int buf = 0;
#pragma unroll 2
  for (int it = 0; it < 32; ++it) {
    const int par = it & 1;                   // folds static under unroll 2
    // writer's ds_writes visible to all after this barrier
    asm volatile("s_waitcnt lgkmcnt(0)" ::: "memory");
    __builtin_amdgcn_s_barrier();
    __builtin_amdgcn_sched_barrier(0);
    const int sb = buf ? buf - 1 : 2;         // (it+2) % 3
    const int wb = (buf == 2) ? 0 : buf + 1;  // (it+1) % 3
    if (it < 30) {
      const int kn = (it + 2) * 32;
#pragma unroll
      for (int c = 0; c < 2; ++c)
        gload_lds16(wt + (size_t)(n0 + srow[c]) * D_MODEL + kn + scl[c] * 8, &Bs[sb][(w * 2 + c) * 512]);
#pragma unroll
      for (int c = 0; c < 2; ++c) {
        const float* xrow = x + (size_t)(m0 + srow[c]) * D_MODEL + kn + scl[c] * 8;
        pA[par][c * 2 + 0] = ((const float4*)xrow)[0];
        pA[par][c * 2 + 1] = ((const float4*)xrow)[1];
      }
      asm volatile("s_waitcnt vmcnt(6)" ::: "memory");   // retire through A(it+1)
    } else {
      asm volatile("s_waitcnt vmcnt(0)" ::: "memory");
    }
    if (it < 31) {                            // ds_write A(it+1) into As[wb]
      const int wpar = par ^ 1;
#pragma unroll
      for (int c = 0; c < 2; ++c) {
        f16x8 hv;
        const float4 a = pA[wpar][c * 2], b2 = pA[wpar][c * 2 + 1];
        hv[0] = (f16)a.x;  hv[1] = (f16)a.y;  hv[2] = (f16)a.z;  hv[3] = (f16)a.w;
        hv[4] = (f16)b2.x; hv[5] = (f16)b2.y; hv[6] = (f16)b2.z; hv[7] = (f16)b2.w;
        *(f16x8*)(&As[wb][(w * 2 + c) * 512 + lane * 8]) = hv;
      }
    }
    f16x8 aC[4], bC[4];
#pragma unroll
    for (int mt = 0; mt < 4; ++mt) aC[mt] = *(const f16x8*)(&As[buf][aoff + mt * 512]);
#pragma unroll
    for (int nt = 0; nt < 4; ++nt) bC[nt] = *(const f16x8*)(&Bs[buf][boff + nt * 512]);
    if (it) {
#pragma unroll
      for (int mt = 0; mt < 4; ++mt)
#pragma unroll
        for (int nt = 0; nt < 4; ++nt)
          acc[mt][nt] = __builtin_amdgcn_mfma_f32_16x16x32_f16(aP[mt], bP[nt], acc[mt][nt], 0, 0, 0);
    }
#pragma unroll
    for (int tt = 0; tt < 4; ++tt) { aP[tt] = aC[tt]; bP[tt] = bC[tt]; }
    buf = wb;
  }
#pragma unroll
  for (int mt = 0; mt < 4; ++mt)
#pragma unroll
    for (int nt = 0; nt < 4; ++nt)
      acc[mt][nt] = __builtin_amdgcn_mfma_f32_16x16x32_f16(aP[mt], bP[nt], acc[mt][nt], 0, 0, 0);

  const float sc = (z == 0) ? SSCALE : 1.0f;
  float bcol[4];
#pragma unroll
  for (int nt = 0; nt < 4; ++nt) bcol[nt] = bias[n0 + wn * 64 + nt * 16 + l15];

  if (z < 2) {
    f16* out = (z == 0) ? qout : kout;
#pragma unroll
    for (int mt = 0; mt < 4; ++mt) {
      int mbase = m0 + wm * 64 + mt * 16 + quad * 4;
#pragma unroll
      for (int nt = 0; nt < 4; ++nt) {
        int n = n0 + wn * 64 + nt * 16 + l15;
        int h = n >> 6, dh = n & 63;
#pragma unroll
        for (int r = 0; r < 4; ++r) {
          int m = mbase + r;
          int b = m >> 11, s = m & 2047;
          out[((size_t)(b * HEADS + h) * SEQ + s) * DH + dh] = (f16)((acc[mt][nt][r] + bcol[nt]) * sc);
        }
      }
    }
  } else {
    // V in PV-fragment order: per (bh,kt) 4096-elem tile, row dh (64 elems),
    // sk' = quad*16 + mt*4 + r, phys 8-elem chunk = (sk'>>3) ^ (dh&7).
#pragma unroll
    for (int mt = 0; mt < 4; ++mt) {
      int mbase = m0 + wm * 64 + mt * 16 + quad * 4;
      int b = mbase >> 11, seq = mbase & 2047;
      int kt = seq >> 6;
#pragma unroll
      for (int nt = 0; nt < 4; ++nt) {
        int n = n0 + wn * 64 + nt * 16 + l15;
        int h = n >> 6, dh = n & 63;
        f16x4 v;
#pragma unroll
        for (int r = 0; r < 4; ++r) v[r] = (f16)(acc[mt][nt][r] + bcol[nt]);
        int phys = (quad * 2 + (mt >> 1)) ^ (dh & 7);
        size_t off = (((size_t)(b * HEADS + h) * 32 + kt) * 4096) + dh * 64 + phys * 8 + (mt & 1) * 4;
        *(f16x4*)(vtout + off) = v;
      }
    }
  }
}

// ---------------- fused flash attention (round-0 body verbatim: best measured 92.2us) ----------------
__global__ __launch_bounds__(256, 2) void attn_kernel(
    const f16* __restrict__ q, const f16* __restrict__ k, const f16* __restrict__ vt,
    float* __restrict__ out) {
  const int bh = blockIdx.x;             // (bh, qtile): q-tiles of one head share an XCD
  const int s0 = blockIdx.y * 256;
  const int b = bh >> 4, h = bh & 15;
  const int tid = threadIdx.x, lane = tid & 63, w = tid >> 6;
  const int quad = lane >> 4, l15 = lane & 15;

  __shared__ f16 Ks[2][64 * 64];   // [sk][dh], 8KB per buffer
  __shared__ f16 Vs[2][64 * 64];   // PV-fragment order, 8KB per buffer

  const f16* qbase = q + ((size_t)bh * SEQ + s0 + w * 64) * DH;
  const f16* kbase = k + (size_t)bh * SEQ * DH;
  const f16* vbase = vt + (size_t)bh * DH * SEQ;   // tile kt at +kt*4096

  // Q fragments: 4 q-subtiles of 16 per wave
  f16x8 qf[4][2];
#pragma unroll
  for (int qt = 0; qt < 4; ++qt)
#pragma unroll
    for (int ks = 0; ks < 2; ++ks)
      qf[qt][ks] = *(const f16x8*)(qbase + (qt * 16 + l15) * DH + ks * 32 + quad * 8);

  int koff[2];
  koff[0] = l15 * 64 + ((quad ^ (l15 & 7)) * 8);
  koff[1] = l15 * 64 + (((4 + quad) ^ (l15 & 7)) * 8);
  int voff2[2];                    // V b128 reads: half h covers ks=2h,2h+1
  voff2[0] = l15 * 64 + (((quad * 2) ^ (l15 & 7)) * 8);
  voff2[1] = l15 * 64 + (((quad * 2 + 1) ^ (l15 & 7)) * 8);

  int srow[2], scl[2];             // K staging swizzle (V staging is identity)
#pragma unroll
  for (int c = 0; c < 2; ++c) {
    int slot = (w * 2 + c) * 64 + lane;
    srow[c] = slot >> 3;
    scl[c] = (slot & 7) ^ (srow[c] & 7);
  }
  const int vslot = ((w * 2) * 64 + lane) * 8;   // identity V staging offsets
  const int vslot2 = ((w * 2 + 1) * 64 + lane) * 8;

  f32x4 lsum4[4];
#pragma unroll
  for (int qt = 0; qt < 4; ++qt) lsum4[qt] = (f32x4){0.f, 0.f, 0.f, 0.f};
  f32x4 o[4][4];
#pragma unroll
  for (int i = 0; i < 4; ++i)
#pragma unroll
    for (int jj = 0; jj < 4; ++jj) o[i][jj] = (f32x4){0.f, 0.f, 0.f, 0.f};
  const f32x4 Zero = (f32x4){0.f, 0.f, 0.f, 0.f};

  // prologue: stage kt=0 into buf 0
#pragma unroll
  for (int c = 0; c < 2; ++c)
    gload_lds16(kbase + (size_t)srow[c] * DH + scl[c] * 8, &Ks[0][(w * 2 + c) * 512]);
  gload_lds16(vbase + vslot,  &Vs[0][(w * 2) * 512]);
  gload_lds16(vbase + vslot2, &Vs[0][(w * 2 + 1) * 512]);

  for (int kt = 0; kt < SEQ / 64; ++kt) {
    const int buf = kt & 1;
    __syncthreads();                          // this iter's tiles ready (staged last iter)
    if (kt < SEQ / 64 - 1) {
      const int kn = (kt + 1) * 64;
#pragma unroll
      for (int c = 0; c < 2; ++c)
        gload_lds16(kbase + (size_t)(kn + srow[c]) * DH + scl[c] * 8, &Ks[buf ^ 1][(w * 2 + c) * 512]);
      gload_lds16(vbase + (kt + 1) * 4096 + vslot,  &Vs[buf ^ 1][(w * 2) * 512]);
      gload_lds16(vbase + (kt + 1) * 4096 + vslot2, &Vs[buf ^ 1][(w * 2 + 1) * 512]);
    }

    // S^T = K·Q^T (Q pre-scaled into log2 domain); 4 sk-tiles x 4 q-tiles
    f32x4 st[4][4];
#pragma unroll
    for (int mt = 0; mt < 4; ++mt) {
      f16x8 af0 = *(const f16x8*)(&Ks[buf][koff[0] + mt * 1024]);
      f16x8 af1 = *(const f16x8*)(&Ks[buf][koff[1] + mt * 1024]);
#pragma unroll
      for (int qt = 0; qt < 4; ++qt) {
        st[mt][qt] = __builtin_amdgcn_mfma_f32_16x16x32_f16(af0, qf[qt][0], Zero, 0, 0, 0);
        st[mt][qt] = __builtin_amdgcn_mfma_f32_16x16x32_f16(af1, qf[qt][1], st[mt][qt], 0, 0, 0);
      }
    }

    // exp2 + pack all 4 ks-chunks; lsum accumulated as f32x4 vector
    f16x4 pb[4][4];
#pragma unroll
    for (int ks = 0; ks < 4; ++ks)
#pragma unroll
      for (int qt = 0; qt < 4; ++qt) {
        float e0 = __builtin_amdgcn_exp2f(st[ks][qt][0]);
        float e1 = __builtin_amdgcn_exp2f(st[ks][qt][1]);
        float e2 = __builtin_amdgcn_exp2f(st[ks][qt][2]);
        float e3 = __builtin_amdgcn_exp2f(st[ks][qt][3]);
        f32x4 ev = (f32x4){e0, e1, e2, e3};
        lsum4[qt] += ev;
        f16x2 p01 = __builtin_bit_cast(f16x2, __builtin_amdgcn_cvt_pkrtz(e0, e1));
        f16x2 p23 = __builtin_bit_cast(f16x2, __builtin_amdgcn_cvt_pkrtz(e2, e3));
        pb[ks][qt] = __builtin_shufflevector(p01, p23, 0, 1, 2, 3);
      }

    // PV: O^T += V^T·P^T. One b128 per (half,mt) feeds 2 K=16 MFMAs x 4 qt.
#pragma unroll
    for (int half = 0; half < 2; ++half)
#pragma unroll
      for (int mt = 0; mt < 4; ++mt) {
        f16x8 v8 = *(const f16x8*)(&Vs[buf][voff2[half] + mt * 1024]);
        f16x4 vaA = __builtin_shufflevector(v8, v8, 0, 1, 2, 3);
        f16x4 vaB = __builtin_shufflevector(v8, v8, 4, 5, 6, 7);
#pragma unroll
        for (int qt = 0; qt < 4; ++qt) {
          o[mt][qt] = __builtin_amdgcn_mfma_f32_16x16x16f16(vaA, pb[half * 2][qt], o[mt][qt], 0, 0, 0);
          o[mt][qt] = __builtin_amdgcn_mfma_f32_16x16x16f16(vaB, pb[half * 2 + 1][qt], o[mt][qt], 0, 0, 0);
        }
      }
  }

  // epilogue: horizontal + cross-quad l reduce, normalize, store
#pragma unroll
  for (int qt = 0; qt < 4; ++qt) {
    float l = (lsum4[qt][0] + lsum4[qt][1]) + (lsum4[qt][2] + lsum4[qt][3]);
    l += __shfl_xor(l, 16, 64);
    l += __shfl_xor(l, 32, 64);
    float inv = 1.f / l;
    int sq = s0 + w * 64 + qt * 16 + l15;
    float* obase = out + ((size_t)b * SEQ + sq) * D_MODEL + h * DH;
#pragma unroll
    for (int mt = 0; mt < 4; ++mt) {
      f32x4 vv;
#pragma unroll
      for (int r = 0; r < 4; ++r) vv[r] = o[mt][qt][r] * inv;
      *(f32x4*)(obase + mt * 16 + quad * 4) = vv;
    }
  }
}

extern "C" void kernel_launch(void* const* d_in, const int* in_sizes, int n_in,
                              void* d_out, int out_size, void* d_ws, size_t ws_size,
                              hipStream_t stream) {
  const float* x  = (const float*)d_in[0];
  const float* Wq = (const float*)d_in[1];
  const float* bq = (const float*)d_in[2];
  const float* Wk = (const float*)d_in[3];
  const float* bk = (const float*)d_in[4];
  const float* Wv = (const float*)d_in[5];
  const float* bv = (const float*)d_in[6];
  float* out = (float*)d_out;

  char* ws = (char*)d_ws;
  f16* wt = (f16*)(ws + (size_t)16 * 1024 * 1024);
  f16* q  = (f16*)(ws + (size_t)22 * 1024 * 1024);
  f16* kk = q + (size_t)BATCH * SEQ * D_MODEL;
  f16* vt = kk + (size_t)BATCH * SEQ * D_MODEL;

  prep_kernel<<<768, 256, 0, stream>>>(Wq, Wk, Wv, wt);
  qkv_gemm_kernel<<<1536, 256, 0, stream>>>(x, wt, bq, bk, bv, q, kk, vt);
  attn_kernel<<<dim3(64, 8), 256, 0, stream>>>(q, kk, vt, out);
}

// Round 7
// 276.275 us; speedup vs baseline: 1.6679x; 1.6679x over previous
//
#include <hip/hip_runtime.h>

typedef _Float16 f16;
typedef __attribute__((ext_vector_type(2))) _Float16 f16x2;
typedef __attribute__((ext_vector_type(2))) __fp16   hf16x2;  // cvt_pkrtz native return
typedef __attribute__((ext_vector_type(4))) _Float16 f16x4;
typedef __attribute__((ext_vector_type(8))) _Float16 f16x8;
typedef __attribute__((ext_vector_type(4))) float    f32x4;

#define D_MODEL 1024
#define HEADS   16
#define DH      64
#define SEQ     2048
#define BATCH   4
#define SSCALE  0.1803368801111204f   // 1/sqrt(64) * log2(e)

// async 16B global->LDS; lds dst is wave-uniform base + lane*16
__device__ __forceinline__ void gload_lds16(const void* g, void* lds) {
  __builtin_amdgcn_global_load_lds(
      (const __attribute__((address_space(1))) unsigned int*)g,
      (__attribute__((address_space(3))) unsigned int*)lds, 16, 0, 0);
}

// ---------------- prep: cast x, transpose W (merged: one dispatch; r0 form) ----------------
__global__ __launch_bounds__(256) void prep_kernel(const float* __restrict__ x,
                                                   const float* __restrict__ Wq,
                                                   const float* __restrict__ Wk,
                                                   const float* __restrict__ Wv,
                                                   f16* __restrict__ xb,
                                                   f16* __restrict__ wt) {
  if (blockIdx.x < 8192) {                     // cast x fp32 -> f16
    int i = blockIdx.x * 256 + threadIdx.x;
    float4 v = ((const float4*)x)[i];
    f16x4 h;
    h[0] = (f16)v.x; h[1] = (f16)v.y; h[2] = (f16)v.z; h[3] = (f16)v.w;
    ((f16x4*)xb)[i] = h;
    return;
  }
  int bid = blockIdx.x - 8192;                 // W [K][N] fp32 -> Wt [N][K] f16
  int z = bid >> 8, rem = bid & 255;
  const float* W = z == 0 ? Wq : (z == 1 ? Wk : Wv);
  f16* out = wt + (size_t)z * D_MODEL * D_MODEL;
  __shared__ float tile[64][65];
  int n0 = (rem & 15) * 64, k0 = (rem >> 4) * 64;
  int tx = threadIdx.x & 63, ty = threadIdx.x >> 6;
#pragma unroll
  for (int r = 0; r < 16; ++r)
    tile[ty * 16 + r][tx] = W[(size_t)(k0 + ty * 16 + r) * D_MODEL + n0 + tx];
  __syncthreads();
#pragma unroll
  for (int r = 0; r < 16; ++r)
    out[(size_t)(n0 + ty * 16 + r) * D_MODEL + k0 + tx] = (f16)tile[tx][ty * 16 + r];
}

// ---------------- QKV projection GEMM ----------------
// 128x128 tile, BK=32. r4 structure (XCD m-band remap, B ring-3 + counted
// vmcnt) MINUS the A-side LDS: qkv was LDS-pipe-bound (8 ds_read + 4
// lds-write per wave-step ~ 45us of pipe time). A-fragments are now DIRECT
// global->reg b128 loads (verified identical bytes to the old staged path:
// the staging and read XOR-swizzles cancel; row = wm*64+mt*16+l15, chunk =
// quad). A is 2-way wave-shared -> 2x L2 reads (cheap); LDS ops/wave-step
// drop 12 -> 6. Named parity buffers aR0/aR1 + two-phase body = all indices
// compile-time (NO scratch; r6's rule-#20 failure mode avoided).
// vmcnt: 6 VMEM/iter (4 A-loads + 2 B-gload_lds). Pre-barrier vmcnt(6)
// retires batch t-2 (incl. B(t)) and keeps batch t-1 airborne.
__global__ __launch_bounds__(256, 3) void qkv_gemm_kernel(
    const f16* __restrict__ xb, const f16* __restrict__ wt_all,
    const float* __restrict__ bq, const float* __restrict__ bk, const float* __restrict__ bv,
    f16* __restrict__ qout, f16* __restrict__ kout, f16* __restrict__ vtout) {
  const int bid = blockIdx.x;
  const int j = bid & 7, t = bid >> 3;
  const int by = j * 8 + (t & 7);            // m-block: contiguous band per XCD
  const int bx = (t >> 3) & 7;               // n-block
  const int z  = t >> 6;                     // q/k/v
  const f16* wt = wt_all + (size_t)z * D_MODEL * D_MODEL;
  const float* bias = z == 0 ? bq : (z == 1 ? bk : bv);
  const int n0 = bx * 128, m0 = by * 128;

  __shared__ f16 Bs[3][128 * 32];   // 8KB per buffer, ring-3 (24KB total)

  const int tid = threadIdx.x;
  const int lane = tid & 63, w = tid >> 6;
  const int quad = lane >> 4, l15 = lane & 15;
  const int wm = w & 1, wn = w >> 1;

  const int pce = (quad ^ ((l15 >> 1) & 3)) * 8;
  const int boff = wn * 2048 + l15 * 32 + pce;

  int srow[2], scl[2];
#pragma unroll
  for (int c = 0; c < 2; ++c) {
    int slot = (w * 2 + c) * 64 + lane;
    srow[c] = slot >> 2;
    scl[c] = (slot & 3) ^ ((srow[c] >> 1) & 3);
  }

  f32x4 acc[4][4];
#pragma unroll
  for (int i = 0; i < 4; ++i)
#pragma unroll
    for (int jj = 0; jj < 4; ++jj) acc[i][jj] = (f32x4){0.f, 0.f, 0.f, 0.f};

  // A global fragment row bases (per mt): 16B per lane, k-contiguous
  const f16* arow[4];
#pragma unroll
  for (int mt = 0; mt < 4; ++mt)
    arow[mt] = xb + (size_t)(m0 + wm * 64 + mt * 16 + l15) * D_MODEL + quad * 8;

  // prologue: stage B(0), B(1)
#pragma unroll
  for (int tt = 0; tt < 2; ++tt)
#pragma unroll
    for (int c = 0; c < 2; ++c)
      gload_lds16(wt + (size_t)(n0 + srow[c]) * D_MODEL + tt * 32 + scl[c] * 8, &Bs[tt][(w * 2 + c) * 512]);

  f16x8 aR0[4], aR1[4], bP[4];
  int buf = 0;

  auto body = [&](int it, f16x8 (&aIss)[4], f16x8 (&aCon)[4]) {
    if (it == 0)       { asm volatile("s_waitcnt vmcnt(2)" ::: "memory"); }
    else if (it == 31) { asm volatile("s_waitcnt vmcnt(0)" ::: "memory"); }
    else               { asm volatile("s_waitcnt vmcnt(6)" ::: "memory"); }
    __builtin_amdgcn_s_barrier();
    __builtin_amdgcn_sched_barrier(0);        // pin: nothing crosses the barrier
    // issue A(it): 4 direct b128 loads into the issue-parity regs
#pragma unroll
    for (int mt = 0; mt < 4; ++mt)
      aIss[mt] = *(const f16x8*)(arow[mt] + it * 32);
    // stage B(it+2)
    if (it < 30) {
      const int sb = buf ? buf - 1 : 2;       // (it+2) % 3
      const int kn = (it + 2) * 32;
#pragma unroll
      for (int c = 0; c < 2; ++c)
        gload_lds16(wt + (size_t)(n0 + srow[c]) * D_MODEL + kn + scl[c] * 8, &Bs[sb][(w * 2 + c) * 512]);
    }
    // read B(it) fragments from LDS
    f16x8 bC[4];
#pragma unroll
    for (int nt = 0; nt < 4; ++nt) bC[nt] = *(const f16x8*)(&Bs[buf][boff + nt * 512]);
    // MFMA on tile it-1 (aCon = A(it-1), bP = B(it-1))
    if (it) {
#pragma unroll
      for (int mt = 0; mt < 4; ++mt)
#pragma unroll
        for (int nt = 0; nt < 4; ++nt)
          acc[mt][nt] = __builtin_amdgcn_mfma_f32_16x16x32_f16(aCon[mt], bP[nt], acc[mt][nt], 0, 0, 0);
    }
#pragma unroll
    for (int nt = 0; nt < 4; ++nt) bP[nt] = bC[nt];
    buf = (buf == 2) ? 0 : buf + 1;
  };

  for (int ih = 0; ih < 16; ++ih) {
    body(2 * ih,     aR0, aR1);
    body(2 * ih + 1, aR1, aR0);
  }
  // final MFMA: tile 31 (A(31) sits in aR1 — issued in the last odd body)
#pragma unroll
  for (int mt = 0; mt < 4; ++mt)
#pragma unroll
    for (int nt = 0; nt < 4; ++nt)
      acc[mt][nt] = __builtin_amdgcn_mfma_f32_16x16x32_f16(aR1[mt], bP[nt], acc[mt][nt], 0, 0, 0);

  const float sc = (z == 0) ? SSCALE : 1.0f;
  float bcol[4];
#pragma unroll
  for (int nt = 0; nt < 4; ++nt) bcol[nt] = bias[n0 + wn * 64 + nt * 16 + l15];

  if (z < 2) {
    f16* out = (z == 0) ? qout : kout;
#pragma unroll
    for (int mt = 0; mt < 4; ++mt) {
      int mbase = m0 + wm * 64 + mt * 16 + quad * 4;
#pragma unroll
      for (int nt = 0; nt < 4; ++nt) {
        int n = n0 + wn * 64 + nt * 16 + l15;
        int h = n >> 6, dh = n & 63;
#pragma unroll
        for (int r = 0; r < 4; ++r) {
          int m = mbase + r;
          int b = m >> 11, s = m & 2047;
          out[((size_t)(b * HEADS + h) * SEQ + s) * DH + dh] = (f16)((acc[mt][nt][r] + bcol[nt]) * sc);
        }
      }
    }
  } else {
    // V in PV-fragment order: per (bh,kt) 4096-elem tile, row dh (64 elems),
    // sk' = quad*16 + mt*4 + r, phys 8-elem chunk = (sk'>>3) ^ (dh&7).
#pragma unroll
    for (int mt = 0; mt < 4; ++mt) {
      int mbase = m0 + wm * 64 + mt * 16 + quad * 4;
      int b = mbase >> 11, seq = mbase & 2047;
      int kt = seq >> 6;
#pragma unroll
      for (int nt = 0; nt < 4; ++nt) {
        int n = n0 + wn * 64 + nt * 16 + l15;
        int h = n >> 6, dh = n & 63;
        f16x4 v;
#pragma unroll
        for (int r = 0; r < 4; ++r) v[r] = (f16)(acc[mt][nt][r] + bcol[nt]);
        int phys = (quad * 2 + (mt >> 1)) ^ (dh & 7);
        size_t off = (((size_t)(b * HEADS + h) * 32 + kt) * 4096) + dh * 64 + phys * 8 + (mt & 1) * 4;
        *(f16x4*)(vtout + off) = v;
      }
    }
  }
}

// ---------------- fused flash attention (round-0 body verbatim: best measured 92.2us) ----------------
__global__ __launch_bounds__(256, 2) void attn_kernel(
    const f16* __restrict__ q, const f16* __restrict__ k, const f16* __restrict__ vt,
    float* __restrict__ out) {
  const int bh = blockIdx.x;             // (bh, qtile): q-tiles of one head share an XCD
  const int s0 = blockIdx.y * 256;
  const int b = bh >> 4, h = bh & 15;
  const int tid = threadIdx.x, lane = tid & 63, w = tid >> 6;
  const int quad = lane >> 4, l15 = lane & 15;

  __shared__ f16 Ks[2][64 * 64];   // [sk][dh], 8KB per buffer
  __shared__ f16 Vs[2][64 * 64];   // PV-fragment order, 8KB per buffer

  const f16* qbase = q + ((size_t)bh * SEQ + s0 + w * 64) * DH;
  const f16* kbase = k + (size_t)bh * SEQ * DH;
  const f16* vbase = vt + (size_t)bh * DH * SEQ;   // tile kt at +kt*4096

  // Q fragments: 4 q-subtiles of 16 per wave
  f16x8 qf[4][2];
#pragma unroll
  for (int qt = 0; qt < 4; ++qt)
#pragma unroll
    for (int ks = 0; ks < 2; ++ks)
      qf[qt][ks] = *(const f16x8*)(qbase + (qt * 16 + l15) * DH + ks * 32 + quad * 8);

  int koff[2];
  koff[0] = l15 * 64 + ((quad ^ (l15 & 7)) * 8);
  koff[1] = l15 * 64 + (((4 + quad) ^ (l15 & 7)) * 8);
  int voff2[2];                    // V b128 reads: half h covers ks=2h,2h+1
  voff2[0] = l15 * 64 + (((quad * 2) ^ (l15 & 7)) * 8);
  voff2[1] = l15 * 64 + (((quad * 2 + 1) ^ (l15 & 7)) * 8);

  int srow[2], scl[2];             // K staging swizzle (V staging is identity)
#pragma unroll
  for (int c = 0; c < 2; ++c) {
    int slot = (w * 2 + c) * 64 + lane;
    srow[c] = slot >> 3;
    scl[c] = (slot & 7) ^ (srow[c] & 7);
  }
  const int vslot = ((w * 2) * 64 + lane) * 8;   // identity V staging offsets
  const int vslot2 = ((w * 2 + 1) * 64 + lane) * 8;

  f32x4 lsum4[4];
#pragma unroll
  for (int qt = 0; qt < 4; ++qt) lsum4[qt] = (f32x4){0.f, 0.f, 0.f, 0.f};
  f32x4 o[4][4];
#pragma unroll
  for (int i = 0; i < 4; ++i)
#pragma unroll
    for (int jj = 0; jj < 4; ++jj) o[i][jj] = (f32x4){0.f, 0.f, 0.f, 0.f};
  const f32x4 Zero = (f32x4){0.f, 0.f, 0.f, 0.f};

  // prologue: stage kt=0 into buf 0
#pragma unroll
  for (int c = 0; c < 2; ++c)
    gload_lds16(kbase + (size_t)srow[c] * DH + scl[c] * 8, &Ks[0][(w * 2 + c) * 512]);
  gload_lds16(vbase + vslot,  &Vs[0][(w * 2) * 512]);
  gload_lds16(vbase + vslot2, &Vs[0][(w * 2 + 1) * 512]);

  for (int kt = 0; kt < SEQ / 64; ++kt) {
    const int buf = kt & 1;
    __syncthreads();                          // this iter's tiles ready (staged last iter)
    if (kt < SEQ / 64 - 1) {
      const int kn = (kt + 1) * 64;
#pragma unroll
      for (int c = 0; c < 2; ++c)
        gload_lds16(kbase + (size_t)(kn + srow[c]) * DH + scl[c] * 8, &Ks[buf ^ 1][(w * 2 + c) * 512]);
      gload_lds16(vbase + (kt + 1) * 4096 + vslot,  &Vs[buf ^ 1][(w * 2) * 512]);
      gload_lds16(vbase + (kt + 1) * 4096 + vslot2, &Vs[buf ^ 1][(w * 2 + 1) * 512]);
    }

    // S^T = K·Q^T (Q pre-scaled into log2 domain); 4 sk-tiles x 4 q-tiles
    f32x4 st[4][4];
#pragma unroll
    for (int mt = 0; mt < 4; ++mt) {
      f16x8 af0 = *(const f16x8*)(&Ks[buf][koff[0] + mt * 1024]);
      f16x8 af1 = *(const f16x8*)(&Ks[buf][koff[1] + mt * 1024]);
#pragma unroll
      for (int qt = 0; qt < 4; ++qt) {
        st[mt][qt] = __builtin_amdgcn_mfma_f32_16x16x32_f16(af0, qf[qt][0], Zero, 0, 0, 0);
        st[mt][qt] = __builtin_amdgcn_mfma_f32_16x16x32_f16(af1, qf[qt][1], st[mt][qt], 0, 0, 0);
      }
    }

    // exp2 + pack all 4 ks-chunks; lsum accumulated as f32x4 vector
    f16x4 pb[4][4];
#pragma unroll
    for (int ks = 0; ks < 4; ++ks)
#pragma unroll
      for (int qt = 0; qt < 4; ++qt) {
        float e0 = __builtin_amdgcn_exp2f(st[ks][qt][0]);
        float e1 = __builtin_amdgcn_exp2f(st[ks][qt][1]);
        float e2 = __builtin_amdgcn_exp2f(st[ks][qt][2]);
        float e3 = __builtin_amdgcn_exp2f(st[ks][qt][3]);
        f32x4 ev = (f32x4){e0, e1, e2, e3};
        lsum4[qt] += ev;
        f16x2 p01 = __builtin_bit_cast(f16x2, __builtin_amdgcn_cvt_pkrtz(e0, e1));
        f16x2 p23 = __builtin_bit_cast(f16x2, __builtin_amdgcn_cvt_pkrtz(e2, e3));
        pb[ks][qt] = __builtin_shufflevector(p01, p23, 0, 1, 2, 3);
      }

    // PV: O^T += V^T·P^T. One b128 per (half,mt) feeds 2 K=16 MFMAs x 4 qt.
#pragma unroll
    for (int half = 0; half < 2; ++half)
#pragma unroll
      for (int mt = 0; mt < 4; ++mt) {
        f16x8 v8 = *(const f16x8*)(&Vs[buf][voff2[half] + mt * 1024]);
        f16x4 vaA = __builtin_shufflevector(v8, v8, 0, 1, 2, 3);
        f16x4 vaB = __builtin_shufflevector(v8, v8, 4, 5, 6, 7);
#pragma unroll
        for (int qt = 0; qt < 4; ++qt) {
          o[mt][qt] = __builtin_amdgcn_mfma_f32_16x16x16f16(vaA, pb[half * 2][qt], o[mt][qt], 0, 0, 0);
          o[mt][qt] = __builtin_amdgcn_mfma_f32_16x16x16f16(vaB, pb[half * 2 + 1][qt], o[mt][qt], 0, 0, 0);
        }
      }
  }

  // epilogue: horizontal + cross-quad l reduce, normalize, store
#pragma unroll
  for (int qt = 0; qt < 4; ++qt) {
    float l = (lsum4[qt][0] + lsum4[qt][1]) + (lsum4[qt][2] + lsum4[qt][3]);
    l += __shfl_xor(l, 16, 64);
    l += __shfl_xor(l, 32, 64);
    float inv = 1.f / l;
    int sq = s0 + w * 64 + qt * 16 + l15;
    float* obase = out + ((size_t)b * SEQ + sq) * D_MODEL + h * DH;
#pragma unroll
    for (int mt = 0; mt < 4; ++mt) {
      f32x4 vv;
#pragma unroll
      for (int r = 0; r < 4; ++r) vv[r] = o[mt][qt][r] * inv;
      *(f32x4*)(obase + mt * 16 + quad * 4) = vv;
    }
  }
}

extern "C" void kernel_launch(void* const* d_in, const int* in_sizes, int n_in,
                              void* d_out, int out_size, void* d_ws, size_t ws_size,
                              hipStream_t stream) {
  const float* x  = (const float*)d_in[0];
  const float* Wq = (const float*)d_in[1];
  const float* bq = (const float*)d_in[2];
  const float* Wk = (const float*)d_in[3];
  const float* bk = (const float*)d_in[4];
  const float* Wv = (const float*)d_in[5];
  const float* bv = (const float*)d_in[6];
  float* out = (float*)d_out;

  char* ws = (char*)d_ws;
  f16* xb = (f16*)ws;
  f16* wt = (f16*)(ws + (size_t)16 * 1024 * 1024);
  f16* q  = (f16*)(ws + (size_t)22 * 1024 * 1024);
  f16* kk = q + (size_t)BATCH * SEQ * D_MODEL;
  f16* vt = kk + (size_t)BATCH * SEQ * D_MODEL;

  prep_kernel<<<8192 + 768, 256, 0, stream>>>(x, Wq, Wk, Wv, xb, wt);
  qkv_gemm_kernel<<<1536, 256, 0, stream>>>(xb, wt, bq, bk, bv, q, kk, vt);
  attn_kernel<<<dim3(64, 8), 256, 0, stream>>>(q, kk, vt, out);
}

// Round 8
// 247.219 us; speedup vs baseline: 1.8640x; 1.1175x over previous
//
#include <hip/hip_runtime.h>

typedef _Float16 f16;
typedef __attribute__((ext_vector_type(2))) _Float16 f16x2;
typedef __attribute__((ext_vector_type(2))) __fp16   hf16x2;  // cvt_pkrtz native return
typedef __attribute__((ext_vector_type(4))) _Float16 f16x4;
typedef __attribute__((ext_vector_type(8))) _Float16 f16x8;
typedef __attribute__((ext_vector_type(4))) float    f32x4;

#define D_MODEL 1024
#define HEADS   16
#define DH      64
#define SEQ     2048
#define BATCH   4
#define SSCALE  0.1803368801111204f   // 1/sqrt(64) * log2(e)

// async 16B global->LDS; lds dst is wave-uniform base + lane*16
__device__ __forceinline__ void gload_lds16(const void* g, void* lds) {
  __builtin_amdgcn_global_load_lds(
      (const __attribute__((address_space(1))) unsigned int*)g,
      (__attribute__((address_space(3))) unsigned int*)lds, 16, 0, 0);
}

// ---------------- prep: cast x, transpose W (merged: one dispatch; r0 form) ----------------
__global__ __launch_bounds__(256) void prep_kernel(const float* __restrict__ x,
                                                   const float* __restrict__ Wq,
                                                   const float* __restrict__ Wk,
                                                   const float* __restrict__ Wv,
                                                   f16* __restrict__ xb,
                                                   f16* __restrict__ wt) {
  if (blockIdx.x < 8192) {                     // cast x fp32 -> f16
    int i = blockIdx.x * 256 + threadIdx.x;
    float4 v = ((const float4*)x)[i];
    f16x4 h;
    h[0] = (f16)v.x; h[1] = (f16)v.y; h[2] = (f16)v.z; h[3] = (f16)v.w;
    ((f16x4*)xb)[i] = h;
    return;
  }
  int bid = blockIdx.x - 8192;                 // W [K][N] fp32 -> Wt [N][K] f16
  int z = bid >> 8, rem = bid & 255;
  const float* W = z == 0 ? Wq : (z == 1 ? Wk : Wv);
  f16* out = wt + (size_t)z * D_MODEL * D_MODEL;
  __shared__ float tile[64][65];
  int n0 = (rem & 15) * 64, k0 = (rem >> 4) * 64;
  int tx = threadIdx.x & 63, ty = threadIdx.x >> 6;
#pragma unroll
  for (int r = 0; r < 16; ++r)
    tile[ty * 16 + r][tx] = W[(size_t)(k0 + ty * 16 + r) * D_MODEL + n0 + tx];
  __syncthreads();
#pragma unroll
  for (int r = 0; r < 16; ++r)
    out[(size_t)(n0 + ty * 16 + r) * D_MODEL + k0 + tx] = (f16)tile[tx][ty * 16 + r];
}

// ---------------- QKV projection GEMM (r4 verbatim: 69.5us measured best) ----------------
// 128x128 tile, BK=32, ring-3 LDS + counted vmcnt(4). XCD-locality remap:
// XCD j (= bid%8) owns a contiguous m-band (y' = j*8 + t%8) -> per-XCD L2
// working set = 2MB xb band + 2MB wt(z). Bijective over 1536 blocks.
__global__ __launch_bounds__(256, 3) void qkv_gemm_kernel(
    const f16* __restrict__ xb, const f16* __restrict__ wt_all,
    const float* __restrict__ bq, const float* __restrict__ bk, const float* __restrict__ bv,
    f16* __restrict__ qout, f16* __restrict__ kout, f16* __restrict__ vtout) {
  const int bid = blockIdx.x;
  const int j = bid & 7, t = bid >> 3;
  const int by = j * 8 + (t & 7);            // m-block: contiguous band per XCD
  const int bx = (t >> 3) & 7;               // n-block
  const int z  = t >> 6;                     // q/k/v
  const f16* wt = wt_all + (size_t)z * D_MODEL * D_MODEL;
  const float* bias = z == 0 ? bq : (z == 1 ? bk : bv);
  const int n0 = bx * 128, m0 = by * 128;

  __shared__ f16 As[3][128 * 32];   // 8KB per buffer, ring-3
  __shared__ f16 Bs[3][128 * 32];   // 48KB total -> still 3 blocks/CU

  const int tid = threadIdx.x;
  const int lane = tid & 63, w = tid >> 6;
  const int quad = lane >> 4, l15 = lane & 15;
  const int wm = w & 1, wn = w >> 1;

  const int pce = (quad ^ ((l15 >> 1) & 3)) * 8;
  const int aoff = wm * 2048 + l15 * 32 + pce;
  const int boff = wn * 2048 + l15 * 32 + pce;

  int srow[2], scl[2];
#pragma unroll
  for (int c = 0; c < 2; ++c) {
    int slot = (w * 2 + c) * 64 + lane;
    srow[c] = slot >> 2;
    scl[c] = (slot & 3) ^ ((srow[c] >> 1) & 3);
  }

  f32x4 acc[4][4];
#pragma unroll
  for (int i = 0; i < 4; ++i)
#pragma unroll
    for (int jj = 0; jj < 4; ++jj) acc[i][jj] = (f32x4){0.f, 0.f, 0.f, 0.f};

  // prologue: stage k-tiles 0 and 1 (issue order: tile0's 4 loads, tile1's 4)
#pragma unroll
  for (int tt = 0; tt < 2; ++tt)
#pragma unroll
    for (int c = 0; c < 2; ++c) {
      gload_lds16(xb + (size_t)(m0 + srow[c]) * D_MODEL + tt * 32 + scl[c] * 8, &As[tt][(w * 2 + c) * 512]);
      gload_lds16(wt + (size_t)(n0 + srow[c]) * D_MODEL + tt * 32 + scl[c] * 8, &Bs[tt][(w * 2 + c) * 512]);
    }

  f16x8 aP[4], bP[4];
  int buf = 0;
  for (int it = 0; it < 32; ++it) {
    // retire through this iter's tile; keep next tile's loads airborne
    if (it == 31) { asm volatile("s_waitcnt vmcnt(0)" ::: "memory"); }
    else          { asm volatile("s_waitcnt vmcnt(4)" ::: "memory"); }
    __builtin_amdgcn_s_barrier();
    __builtin_amdgcn_sched_barrier(0);        // pin: nothing crosses the barrier
    if (it < 30) {
      const int sb = buf ? buf - 1 : 2;       // (it+2) % 3
      const int kn = (it + 2) * 32;
#pragma unroll
      for (int c = 0; c < 2; ++c) {
        gload_lds16(xb + (size_t)(m0 + srow[c]) * D_MODEL + kn + scl[c] * 8, &As[sb][(w * 2 + c) * 512]);
        gload_lds16(wt + (size_t)(n0 + srow[c]) * D_MODEL + kn + scl[c] * 8, &Bs[sb][(w * 2 + c) * 512]);
      }
    }
    f16x8 aC[4], bC[4];
#pragma unroll
    for (int mt = 0; mt < 4; ++mt) aC[mt] = *(const f16x8*)(&As[buf][aoff + mt * 512]);
#pragma unroll
    for (int nt = 0; nt < 4; ++nt) bC[nt] = *(const f16x8*)(&Bs[buf][boff + nt * 512]);
    if (it) {
#pragma unroll
      for (int mt = 0; mt < 4; ++mt)
#pragma unroll
        for (int nt = 0; nt < 4; ++nt)
          acc[mt][nt] = __builtin_amdgcn_mfma_f32_16x16x32_f16(aP[mt], bP[nt], acc[mt][nt], 0, 0, 0);
    }
#pragma unroll
    for (int tt = 0; tt < 4; ++tt) { aP[tt] = aC[tt]; bP[tt] = bC[tt]; }
    buf = (buf == 2) ? 0 : buf + 1;
  }
#pragma unroll
  for (int mt = 0; mt < 4; ++mt)
#pragma unroll
    for (int nt = 0; nt < 4; ++nt)
      acc[mt][nt] = __builtin_amdgcn_mfma_f32_16x16x32_f16(aP[mt], bP[nt], acc[mt][nt], 0, 0, 0);

  const float sc = (z == 0) ? SSCALE : 1.0f;
  float bcol[4];
#pragma unroll
  for (int nt = 0; nt < 4; ++nt) bcol[nt] = bias[n0 + wn * 64 + nt * 16 + l15];

  if (z < 2) {
    f16* out = (z == 0) ? qout : kout;
#pragma unroll
    for (int mt = 0; mt < 4; ++mt) {
      int mbase = m0 + wm * 64 + mt * 16 + quad * 4;
#pragma unroll
      for (int nt = 0; nt < 4; ++nt) {
        int n = n0 + wn * 64 + nt * 16 + l15;
        int h = n >> 6, dh = n & 63;
#pragma unroll
        for (int r = 0; r < 4; ++r) {
          int m = mbase + r;
          int b = m >> 11, s = m & 2047;
          out[((size_t)(b * HEADS + h) * SEQ + s) * DH + dh] = (f16)((acc[mt][nt][r] + bcol[nt]) * sc);
        }
      }
    }
  } else {
    // V in PV-fragment order: per (bh,kt) 4096-elem tile, row dh (64 elems),
    // sk' = quad*16 + mt*4 + r, phys 8-elem chunk = (sk'>>3) ^ (dh&7).
#pragma unroll
    for (int mt = 0; mt < 4; ++mt) {
      int mbase = m0 + wm * 64 + mt * 16 + quad * 4;
      int b = mbase >> 11, seq = mbase & 2047;
      int kt = seq >> 6;
#pragma unroll
      for (int nt = 0; nt < 4; ++nt) {
        int n = n0 + wn * 64 + nt * 16 + l15;
        int h = n >> 6, dh = n & 63;
        f16x4 v;
#pragma unroll
        for (int r = 0; r < 4; ++r) v[r] = (f16)(acc[mt][nt][r] + bcol[nt]);
        int phys = (quad * 2 + (mt >> 1)) ^ (dh & 7);
        size_t off = (((size_t)(b * HEADS + h) * 32 + kt) * 4096) + dh * 64 + phys * 8 + (mt & 1) * 4;
        *(f16x4*)(vtout + off) = v;
      }
    }
  }
}

// ---------------- fused flash attention: KVBLK=128 (halve barrier count) ----------------
// r0 compute body per 64-row subtile (verified best), but TWO subtiles per
// barrier: 16 iterations instead of 32 -> half the __syncthreads vmcnt(0)
// drains, and sub=1's ds_read/MFMA stream overlaps sub=0's exp/PV tail.
// LDS 64KB (2 x 16KB K + 2 x 16KB V) -> still exactly 2 blocks/CU.
__global__ __launch_bounds__(256, 2) void attn_kernel(
    const f16* __restrict__ q, const f16* __restrict__ k, const f16* __restrict__ vt,
    float* __restrict__ out) {
  const int bh = blockIdx.x;             // (bh, qtile): q-tiles of one head share an XCD
  const int s0 = blockIdx.y * 256;
  const int b = bh >> 4, h = bh & 15;
  const int tid = threadIdx.x, lane = tid & 63, w = tid >> 6;
  const int quad = lane >> 4, l15 = lane & 15;

  __shared__ f16 Ks[2][128 * 64];  // [sk][dh], 16KB per buffer
  __shared__ f16 Vs[2][128 * 64];  // PV-fragment order (2 contiguous 4096 tiles)

  const f16* qbase = q + ((size_t)bh * SEQ + s0 + w * 64) * DH;
  const f16* kbase = k + (size_t)bh * SEQ * DH;
  const f16* vbase = vt + (size_t)bh * DH * SEQ;   // 64-row tile kt at +kt*4096

  // Q fragments: 4 q-subtiles of 16 per wave
  f16x8 qf[4][2];
#pragma unroll
  for (int qt = 0; qt < 4; ++qt)
#pragma unroll
    for (int ks = 0; ks < 2; ++ks)
      qf[qt][ks] = *(const f16x8*)(qbase + (qt * 16 + l15) * DH + ks * 32 + quad * 8);

  int koff[2];
  koff[0] = l15 * 64 + ((quad ^ (l15 & 7)) * 8);
  koff[1] = l15 * 64 + (((4 + quad) ^ (l15 & 7)) * 8);
  int voff2[2];                    // V b128 reads: half hf covers ks=2hf,2hf+1
  voff2[0] = l15 * 64 + (((quad * 2) ^ (l15 & 7)) * 8);
  voff2[1] = l15 * 64 + (((quad * 2 + 1) ^ (l15 & 7)) * 8);

  int srow[4], scl[4];             // K staging swizzle over 128 rows
#pragma unroll
  for (int c = 0; c < 4; ++c) {
    int slot = (w * 4 + c) * 64 + lane;
    srow[c] = slot >> 3;                       // 0..127
    scl[c] = (slot & 7) ^ (srow[c] & 7);
  }
  int vslotc[4];                   // identity V staging offsets (8192-elem window)
#pragma unroll
  for (int c = 0; c < 4; ++c) vslotc[c] = ((w * 4 + c) * 64 + lane) * 8;

  f32x4 lsum4[4];
#pragma unroll
  for (int qt = 0; qt < 4; ++qt) lsum4[qt] = (f32x4){0.f, 0.f, 0.f, 0.f};
  f32x4 o[4][4];
#pragma unroll
  for (int i = 0; i < 4; ++i)
#pragma unroll
    for (int jj = 0; jj < 4; ++jj) o[i][jj] = (f32x4){0.f, 0.f, 0.f, 0.f};
  const f32x4 Zero = (f32x4){0.f, 0.f, 0.f, 0.f};

  // prologue: stage kt2=0 (128 rows of K, 8192 elems of V) into buf 0
#pragma unroll
  for (int c = 0; c < 4; ++c)
    gload_lds16(kbase + (size_t)srow[c] * DH + scl[c] * 8, &Ks[0][(w * 4 + c) * 512]);
#pragma unroll
  for (int c = 0; c < 4; ++c)
    gload_lds16(vbase + vslotc[c], &Vs[0][(w * 4 + c) * 512]);

  for (int kt2 = 0; kt2 < SEQ / 128; ++kt2) {
    const int buf = kt2 & 1;
    __syncthreads();                          // this iter's tiles ready (staged last iter)
    if (kt2 < SEQ / 128 - 1) {
      const int kn = (kt2 + 1) * 128;
#pragma unroll
      for (int c = 0; c < 4; ++c)
        gload_lds16(kbase + (size_t)(kn + srow[c]) * DH + scl[c] * 8, &Ks[buf ^ 1][(w * 4 + c) * 512]);
#pragma unroll
      for (int c = 0; c < 4; ++c)
        gload_lds16(vbase + (size_t)(kt2 + 1) * 8192 + vslotc[c], &Vs[buf ^ 1][(w * 4 + c) * 512]);
    }

#pragma unroll
    for (int sub = 0; sub < 2; ++sub) {
      const f16* Kb = &Ks[buf][sub * 4096];
      const f16* Vb = &Vs[buf][sub * 4096];

      // S^T = K·Q^T (Q pre-scaled into log2 domain); 4 sk-tiles x 4 q-tiles
      f32x4 st[4][4];
#pragma unroll
      for (int mt = 0; mt < 4; ++mt) {
        f16x8 af0 = *(const f16x8*)(Kb + koff[0] + mt * 1024);
        f16x8 af1 = *(const f16x8*)(Kb + koff[1] + mt * 1024);
#pragma unroll
        for (int qt = 0; qt < 4; ++qt) {
          st[mt][qt] = __builtin_amdgcn_mfma_f32_16x16x32_f16(af0, qf[qt][0], Zero, 0, 0, 0);
          st[mt][qt] = __builtin_amdgcn_mfma_f32_16x16x32_f16(af1, qf[qt][1], st[mt][qt], 0, 0, 0);
        }
      }

      // exp2 + pack all 4 ks-chunks; lsum accumulated as f32x4 vector
      f16x4 pb[4][4];
#pragma unroll
      for (int ks = 0; ks < 4; ++ks)
#pragma unroll
        for (int qt = 0; qt < 4; ++qt) {
          float e0 = __builtin_amdgcn_exp2f(st[ks][qt][0]);
          float e1 = __builtin_amdgcn_exp2f(st[ks][qt][1]);
          float e2 = __builtin_amdgcn_exp2f(st[ks][qt][2]);
          float e3 = __builtin_amdgcn_exp2f(st[ks][qt][3]);
          f32x4 ev = (f32x4){e0, e1, e2, e3};
          lsum4[qt] += ev;
          f16x2 p01 = __builtin_bit_cast(f16x2, __builtin_amdgcn_cvt_pkrtz(e0, e1));
          f16x2 p23 = __builtin_bit_cast(f16x2, __builtin_amdgcn_cvt_pkrtz(e2, e3));
          pb[ks][qt] = __builtin_shufflevector(p01, p23, 0, 1, 2, 3);
        }

      // PV: O^T += V^T·P^T. One b128 per (half,mt) feeds 2 K=16 MFMAs x 4 qt.
#pragma unroll
      for (int half = 0; half < 2; ++half)
#pragma unroll
        for (int mt = 0; mt < 4; ++mt) {
          f16x8 v8 = *(const f16x8*)(Vb + voff2[half] + mt * 1024);
          f16x4 vaA = __builtin_shufflevector(v8, v8, 0, 1, 2, 3);
          f16x4 vaB = __builtin_shufflevector(v8, v8, 4, 5, 6, 7);
#pragma unroll
          for (int qt = 0; qt < 4; ++qt) {
            o[mt][qt] = __builtin_amdgcn_mfma_f32_16x16x16f16(vaA, pb[half * 2][qt], o[mt][qt], 0, 0, 0);
            o[mt][qt] = __builtin_amdgcn_mfma_f32_16x16x16f16(vaB, pb[half * 2 + 1][qt], o[mt][qt], 0, 0, 0);
          }
        }
    }
  }

  // epilogue: horizontal + cross-quad l reduce, normalize, store
#pragma unroll
  for (int qt = 0; qt < 4; ++qt) {
    float l = (lsum4[qt][0] + lsum4[qt][1]) + (lsum4[qt][2] + lsum4[qt][3]);
    l += __shfl_xor(l, 16, 64);
    l += __shfl_xor(l, 32, 64);
    float inv = 1.f / l;
    int sq = s0 + w * 64 + qt * 16 + l15;
    float* obase = out + ((size_t)b * SEQ + sq) * D_MODEL + h * DH;
#pragma unroll
    for (int mt = 0; mt < 4; ++mt) {
      f32x4 vv;
#pragma unroll
      for (int r = 0; r < 4; ++r) vv[r] = o[mt][qt][r] * inv;
      *(f32x4*)(obase + mt * 16 + quad * 4) = vv;
    }
  }
}

extern "C" void kernel_launch(void* const* d_in, const int* in_sizes, int n_in,
                              void* d_out, int out_size, void* d_ws, size_t ws_size,
                              hipStream_t stream) {
  const float* x  = (const float*)d_in[0];
  const float* Wq = (const float*)d_in[1];
  const float* bq = (const float*)d_in[2];
  const float* Wk = (const float*)d_in[3];
  const float* bk = (const float*)d_in[4];
  const float* Wv = (const float*)d_in[5];
  const float* bv = (const float*)d_in[6];
  float* out = (float*)d_out;

  char* ws = (char*)d_ws;
  f16* xb = (f16*)ws;
  f16* wt = (f16*)(ws + (size_t)16 * 1024 * 1024);
  f16* q  = (f16*)(ws + (size_t)22 * 1024 * 1024);
  f16* kk = q + (size_t)BATCH * SEQ * D_MODEL;
  f16* vt = kk + (size_t)BATCH * SEQ * D_MODEL;

  prep_kernel<<<8192 + 768, 256, 0, stream>>>(x, Wq, Wk, Wv, xb, wt);
  qkv_gemm_kernel<<<1536, 256, 0, stream>>>(xb, wt, bq, bk, bv, q, kk, vt);
  attn_kernel<<<dim3(64, 8), 256, 0, stream>>>(q, kk, vt, out);
}

// Round 9
// 244.363 us; speedup vs baseline: 1.8858x; 1.0117x over previous
//
#include <hip/hip_runtime.h>

typedef _Float16 f16;
typedef __attribute__((ext_vector_type(2))) _Float16 f16x2;
typedef __attribute__((ext_vector_type(2))) __fp16   hf16x2;  // cvt_pkrtz native return
typedef __attribute__((ext_vector_type(4))) _Float16 f16x4;
typedef __attribute__((ext_vector_type(8))) _Float16 f16x8;
typedef __attribute__((ext_vector_type(4))) float    f32x4;

#define D_MODEL 1024
#define HEADS   16
#define DH      64
#define SEQ     2048
#define BATCH   4
#define SSCALE  0.1803368801111204f   // 1/sqrt(64) * log2(e)

// async 16B global->LDS; lds dst is wave-uniform base + lane*16
__device__ __forceinline__ void gload_lds16(const void* g, void* lds) {
  __builtin_amdgcn_global_load_lds(
      (const __attribute__((address_space(1))) unsigned int*)g,
      (__attribute__((address_space(3))) unsigned int*)lds, 16, 0, 0);
}

// ---------------- prep: cast x, transpose W (merged: one dispatch; r0 form) ----------------
__global__ __launch_bounds__(256) void prep_kernel(const float* __restrict__ x,
                                                   const float* __restrict__ Wq,
                                                   const float* __restrict__ Wk,
                                                   const float* __restrict__ Wv,
                                                   f16* __restrict__ xb,
                                                   f16* __restrict__ wt) {
  if (blockIdx.x < 8192) {                     // cast x fp32 -> f16
    int i = blockIdx.x * 256 + threadIdx.x;
    float4 v = ((const float4*)x)[i];
    f16x4 h;
    h[0] = (f16)v.x; h[1] = (f16)v.y; h[2] = (f16)v.z; h[3] = (f16)v.w;
    ((f16x4*)xb)[i] = h;
    return;
  }
  int bid = blockIdx.x - 8192;                 // W [K][N] fp32 -> Wt [N][K] f16
  int z = bid >> 8, rem = bid & 255;
  const float* W = z == 0 ? Wq : (z == 1 ? Wk : Wv);
  f16* out = wt + (size_t)z * D_MODEL * D_MODEL;
  __shared__ float tile[64][65];
  int n0 = (rem & 15) * 64, k0 = (rem >> 4) * 64;
  int tx = threadIdx.x & 63, ty = threadIdx.x >> 6;
#pragma unroll
  for (int r = 0; r < 16; ++r)
    tile[ty * 16 + r][tx] = W[(size_t)(k0 + ty * 16 + r) * D_MODEL + n0 + tx];
  __syncthreads();
#pragma unroll
  for (int r = 0; r < 16; ++r)
    out[(size_t)(n0 + ty * 16 + r) * D_MODEL + k0 + tx] = (f16)tile[tx][ty * 16 + r];
}

// ---------------- QKV projection GEMM (r4 verbatim: 69.5us measured best) ----------------
// 128x128 tile, BK=32, ring-3 LDS + counted vmcnt(4). XCD-locality remap:
// XCD j (= bid%8) owns a contiguous m-band (y' = j*8 + t%8) -> per-XCD L2
// working set = 2MB xb band + 2MB wt(z). Bijective over 1536 blocks.
__global__ __launch_bounds__(256, 3) void qkv_gemm_kernel(
    const f16* __restrict__ xb, const f16* __restrict__ wt_all,
    const float* __restrict__ bq, const float* __restrict__ bk, const float* __restrict__ bv,
    f16* __restrict__ qout, f16* __restrict__ kout, f16* __restrict__ vtout) {
  const int bid = blockIdx.x;
  const int j = bid & 7, t = bid >> 3;
  const int by = j * 8 + (t & 7);            // m-block: contiguous band per XCD
  const int bx = (t >> 3) & 7;               // n-block
  const int z  = t >> 6;                     // q/k/v
  const f16* wt = wt_all + (size_t)z * D_MODEL * D_MODEL;
  const float* bias = z == 0 ? bq : (z == 1 ? bk : bv);
  const int n0 = bx * 128, m0 = by * 128;

  __shared__ f16 As[3][128 * 32];   // 8KB per buffer, ring-3
  __shared__ f16 Bs[3][128 * 32];   // 48KB total -> still 3 blocks/CU

  const int tid = threadIdx.x;
  const int lane = tid & 63, w = tid >> 6;
  const int quad = lane >> 4, l15 = lane & 15;
  const int wm = w & 1, wn = w >> 1;

  const int pce = (quad ^ ((l15 >> 1) & 3)) * 8;
  const int aoff = wm * 2048 + l15 * 32 + pce;
  const int boff = wn * 2048 + l15 * 32 + pce;

  int srow[2], scl[2];
#pragma unroll
  for (int c = 0; c < 2; ++c) {
    int slot = (w * 2 + c) * 64 + lane;
    srow[c] = slot >> 2;
    scl[c] = (slot & 3) ^ ((srow[c] >> 1) & 3);
  }

  f32x4 acc[4][4];
#pragma unroll
  for (int i = 0; i < 4; ++i)
#pragma unroll
    for (int jj = 0; jj < 4; ++jj) acc[i][jj] = (f32x4){0.f, 0.f, 0.f, 0.f};

  // prologue: stage k-tiles 0 and 1 (issue order: tile0's 4 loads, tile1's 4)
#pragma unroll
  for (int tt = 0; tt < 2; ++tt)
#pragma unroll
    for (int c = 0; c < 2; ++c) {
      gload_lds16(xb + (size_t)(m0 + srow[c]) * D_MODEL + tt * 32 + scl[c] * 8, &As[tt][(w * 2 + c) * 512]);
      gload_lds16(wt + (size_t)(n0 + srow[c]) * D_MODEL + tt * 32 + scl[c] * 8, &Bs[tt][(w * 2 + c) * 512]);
    }

  f16x8 aP[4], bP[4];
  int buf = 0;
  for (int it = 0; it < 32; ++it) {
    // retire through this iter's tile; keep next tile's loads airborne
    if (it == 31) { asm volatile("s_waitcnt vmcnt(0)" ::: "memory"); }
    else          { asm volatile("s_waitcnt vmcnt(4)" ::: "memory"); }
    __builtin_amdgcn_s_barrier();
    __builtin_amdgcn_sched_barrier(0);        // pin: nothing crosses the barrier
    if (it < 30) {
      const int sb = buf ? buf - 1 : 2;       // (it+2) % 3
      const int kn = (it + 2) * 32;
#pragma unroll
      for (int c = 0; c < 2; ++c) {
        gload_lds16(xb + (size_t)(m0 + srow[c]) * D_MODEL + kn + scl[c] * 8, &As[sb][(w * 2 + c) * 512]);
        gload_lds16(wt + (size_t)(n0 + srow[c]) * D_MODEL + kn + scl[c] * 8, &Bs[sb][(w * 2 + c) * 512]);
      }
    }
    f16x8 aC[4], bC[4];
#pragma unroll
    for (int mt = 0; mt < 4; ++mt) aC[mt] = *(const f16x8*)(&As[buf][aoff + mt * 512]);
#pragma unroll
    for (int nt = 0; nt < 4; ++nt) bC[nt] = *(const f16x8*)(&Bs[buf][boff + nt * 512]);
    if (it) {
#pragma unroll
      for (int mt = 0; mt < 4; ++mt)
#pragma unroll
        for (int nt = 0; nt < 4; ++nt)
          acc[mt][nt] = __builtin_amdgcn_mfma_f32_16x16x32_f16(aP[mt], bP[nt], acc[mt][nt], 0, 0, 0);
    }
#pragma unroll
    for (int tt = 0; tt < 4; ++tt) { aP[tt] = aC[tt]; bP[tt] = bC[tt]; }
    buf = (buf == 2) ? 0 : buf + 1;
  }
#pragma unroll
  for (int mt = 0; mt < 4; ++mt)
#pragma unroll
    for (int nt = 0; nt < 4; ++nt)
      acc[mt][nt] = __builtin_amdgcn_mfma_f32_16x16x32_f16(aP[mt], bP[nt], acc[mt][nt], 0, 0, 0);

  const float sc = (z == 0) ? SSCALE : 1.0f;
  float bcol[4];
#pragma unroll
  for (int nt = 0; nt < 4; ++nt) bcol[nt] = bias[n0 + wn * 64 + nt * 16 + l15];

  if (z < 2) {
    f16* out = (z == 0) ? qout : kout;
#pragma unroll
    for (int mt = 0; mt < 4; ++mt) {
      int mbase = m0 + wm * 64 + mt * 16 + quad * 4;
#pragma unroll
      for (int nt = 0; nt < 4; ++nt) {
        int n = n0 + wn * 64 + nt * 16 + l15;
        int h = n >> 6, dh = n & 63;
#pragma unroll
        for (int r = 0; r < 4; ++r) {
          int m = mbase + r;
          int b = m >> 11, s = m & 2047;
          out[((size_t)(b * HEADS + h) * SEQ + s) * DH + dh] = (f16)((acc[mt][nt][r] + bcol[nt]) * sc);
        }
      }
    }
  } else {
    // V in PV-fragment order: per (bh,kt) 4096-elem tile, row dh (64 elems),
    // sk' = quad*16 + mt*4 + r, phys 8-elem chunk = (sk'>>3) ^ (dh&7).
#pragma unroll
    for (int mt = 0; mt < 4; ++mt) {
      int mbase = m0 + wm * 64 + mt * 16 + quad * 4;
      int b = mbase >> 11, seq = mbase & 2047;
      int kt = seq >> 6;
#pragma unroll
      for (int nt = 0; nt < 4; ++nt) {
        int n = n0 + wn * 64 + nt * 16 + l15;
        int h = n >> 6, dh = n & 63;
        f16x4 v;
#pragma unroll
        for (int r = 0; r < 4; ++r) v[r] = (f16)(acc[mt][nt][r] + bcol[nt]);
        int phys = (quad * 2 + (mt >> 1)) ^ (dh & 7);
        size_t off = (((size_t)(b * HEADS + h) * 32 + kt) * 4096) + dh * 64 + phys * 8 + (mt & 1) * 4;
        *(f16x4*)(vtout + off) = v;
      }
    }
  }
}

// ---------------- fused flash attention: 2-wave blocks (4 independent phase domains/CU) ----------------
// r0 compute body verbatim per wave (64 q/wave — LDS reads/CU unchanged), but
// blocks shrink to 2 waves / BQ=128: grid (64,16) = 1024 blocks = 4 blocks/CU
// (4 x 32KB = 128KB LDS). Same 8 waves/CU, but each SIMD's 2 waves now come
// from DIFFERENT barrier domains -> one wave's exp2 (VALU) overlaps the
// other's MFMA instead of both being phase-locked. Costs: 2x K/V refetch
// (L2-hot, same XCD) and 2x LDS-write traffic — both have ample headroom.
__global__ __launch_bounds__(128, 2) void attn_kernel(
    const f16* __restrict__ q, const f16* __restrict__ k, const f16* __restrict__ vt,
    float* __restrict__ out) {
  const int bh = blockIdx.x;             // (bh, qtile): q-tiles of one head share an XCD
  const int s0 = blockIdx.y * 128;
  const int b = bh >> 4, h = bh & 15;
  const int tid = threadIdx.x, lane = tid & 63, w = tid >> 6;   // w in {0,1}
  const int quad = lane >> 4, l15 = lane & 15;

  __shared__ f16 Ks[2][64 * 64];   // [sk][dh], 8KB per buffer
  __shared__ f16 Vs[2][64 * 64];   // PV-fragment order, 8KB per buffer

  const f16* qbase = q + ((size_t)bh * SEQ + s0 + w * 64) * DH;
  const f16* kbase = k + (size_t)bh * SEQ * DH;
  const f16* vbase = vt + (size_t)bh * DH * SEQ;   // tile kt at +kt*4096

  // Q fragments: 4 q-subtiles of 16 per wave
  f16x8 qf[4][2];
#pragma unroll
  for (int qt = 0; qt < 4; ++qt)
#pragma unroll
    for (int ks = 0; ks < 2; ++ks)
      qf[qt][ks] = *(const f16x8*)(qbase + (qt * 16 + l15) * DH + ks * 32 + quad * 8);

  int koff[2];
  koff[0] = l15 * 64 + ((quad ^ (l15 & 7)) * 8);
  koff[1] = l15 * 64 + (((4 + quad) ^ (l15 & 7)) * 8);
  int voff2[2];                    // V b128 reads: half h covers ks=2h,2h+1
  voff2[0] = l15 * 64 + (((quad * 2) ^ (l15 & 7)) * 8);
  voff2[1] = l15 * 64 + (((quad * 2 + 1) ^ (l15 & 7)) * 8);

  int srow[4], scl[4];             // K staging swizzle: 4 calls/thread (128 thr)
#pragma unroll
  for (int c = 0; c < 4; ++c) {
    int slot = (w * 4 + c) * 64 + lane;
    srow[c] = slot >> 3;
    scl[c] = (slot & 7) ^ (srow[c] & 7);
  }
  int vslot[4];                    // identity V staging offsets: 4 calls/thread
#pragma unroll
  for (int c = 0; c < 4; ++c) vslot[c] = ((w * 4 + c) * 64 + lane) * 8;

  f32x4 lsum4[4];
#pragma unroll
  for (int qt = 0; qt < 4; ++qt) lsum4[qt] = (f32x4){0.f, 0.f, 0.f, 0.f};
  f32x4 o[4][4];
#pragma unroll
  for (int i = 0; i < 4; ++i)
#pragma unroll
    for (int jj = 0; jj < 4; ++jj) o[i][jj] = (f32x4){0.f, 0.f, 0.f, 0.f};
  const f32x4 Zero = (f32x4){0.f, 0.f, 0.f, 0.f};

  // prologue: stage kt=0 into buf 0
#pragma unroll
  for (int c = 0; c < 4; ++c)
    gload_lds16(kbase + (size_t)srow[c] * DH + scl[c] * 8, &Ks[0][(w * 4 + c) * 512]);
#pragma unroll
  for (int c = 0; c < 4; ++c)
    gload_lds16(vbase + vslot[c], &Vs[0][(w * 4 + c) * 512]);

  for (int kt = 0; kt < SEQ / 64; ++kt) {
    const int buf = kt & 1;
    __syncthreads();                          // this iter's tiles ready (staged last iter)
    if (kt < SEQ / 64 - 1) {
      const int kn = (kt + 1) * 64;
#pragma unroll
      for (int c = 0; c < 4; ++c)
        gload_lds16(kbase + (size_t)(kn + srow[c]) * DH + scl[c] * 8, &Ks[buf ^ 1][(w * 4 + c) * 512]);
#pragma unroll
      for (int c = 0; c < 4; ++c)
        gload_lds16(vbase + (kt + 1) * 4096 + vslot[c], &Vs[buf ^ 1][(w * 4 + c) * 512]);
    }

    // S^T = K·Q^T (Q pre-scaled into log2 domain); 4 sk-tiles x 4 q-tiles
    f32x4 st[4][4];
#pragma unroll
    for (int mt = 0; mt < 4; ++mt) {
      f16x8 af0 = *(const f16x8*)(&Ks[buf][koff[0] + mt * 1024]);
      f16x8 af1 = *(const f16x8*)(&Ks[buf][koff[1] + mt * 1024]);
#pragma unroll
      for (int qt = 0; qt < 4; ++qt) {
        st[mt][qt] = __builtin_amdgcn_mfma_f32_16x16x32_f16(af0, qf[qt][0], Zero, 0, 0, 0);
        st[mt][qt] = __builtin_amdgcn_mfma_f32_16x16x32_f16(af1, qf[qt][1], st[mt][qt], 0, 0, 0);
      }
    }

    // exp2 + pack all 4 ks-chunks; lsum accumulated as f32x4 vector
    f16x4 pb[4][4];
#pragma unroll
    for (int ks = 0; ks < 4; ++ks)
#pragma unroll
      for (int qt = 0; qt < 4; ++qt) {
        float e0 = __builtin_amdgcn_exp2f(st[ks][qt][0]);
        float e1 = __builtin_amdgcn_exp2f(st[ks][qt][1]);
        float e2 = __builtin_amdgcn_exp2f(st[ks][qt][2]);
        float e3 = __builtin_amdgcn_exp2f(st[ks][qt][3]);
        f32x4 ev = (f32x4){e0, e1, e2, e3};
        lsum4[qt] += ev;
        f16x2 p01 = __builtin_bit_cast(f16x2, __builtin_amdgcn_cvt_pkrtz(e0, e1));
        f16x2 p23 = __builtin_bit_cast(f16x2, __builtin_amdgcn_cvt_pkrtz(e2, e3));
        pb[ks][qt] = __builtin_shufflevector(p01, p23, 0, 1, 2, 3);
      }

    // PV: O^T += V^T·P^T. One b128 per (half,mt) feeds 2 K=16 MFMAs x 4 qt.
#pragma unroll
    for (int half = 0; half < 2; ++half)
#pragma unroll
      for (int mt = 0; mt < 4; ++mt) {
        f16x8 v8 = *(const f16x8*)(&Vs[buf][voff2[half] + mt * 1024]);
        f16x4 vaA = __builtin_shufflevector(v8, v8, 0, 1, 2, 3);
        f16x4 vaB = __builtin_shufflevector(v8, v8, 4, 5, 6, 7);
#pragma unroll
        for (int qt = 0; qt < 4; ++qt) {
          o[mt][qt] = __builtin_amdgcn_mfma_f32_16x16x16f16(vaA, pb[half * 2][qt], o[mt][qt], 0, 0, 0);
          o[mt][qt] = __builtin_amdgcn_mfma_f32_16x16x16f16(vaB, pb[half * 2 + 1][qt], o[mt][qt], 0, 0, 0);
        }
      }
  }

  // epilogue: horizontal + cross-quad l reduce, normalize, store
#pragma unroll
  for (int qt = 0; qt < 4; ++qt) {
    float l = (lsum4[qt][0] + lsum4[qt][1]) + (lsum4[qt][2] + lsum4[qt][3]);
    l += __shfl_xor(l, 16, 64);
    l += __shfl_xor(l, 32, 64);
    float inv = 1.f / l;
    int sq = s0 + w * 64 + qt * 16 + l15;
    float* obase = out + ((size_t)b * SEQ + sq) * D_MODEL + h * DH;
#pragma unroll
    for (int mt = 0; mt < 4; ++mt) {
      f32x4 vv;
#pragma unroll
      for (int r = 0; r < 4; ++r) vv[r] = o[mt][qt][r] * inv;
      *(f32x4*)(obase + mt * 16 + quad * 4) = vv;
    }
  }
}

extern "C" void kernel_launch(void* const* d_in, const int* in_sizes, int n_in,
                              void* d_out, int out_size, void* d_ws, size_t ws_size,
                              hipStream_t stream) {
  const float* x  = (const float*)d_in[0];
  const float* Wq = (const float*)d_in[1];
  const float* bq = (const float*)d_in[2];
  const float* Wk = (const float*)d_in[3];
  const float* bk = (const float*)d_in[4];
  const float* Wv = (const float*)d_in[5];
  const float* bv = (const float*)d_in[6];
  float* out = (float*)d_out;

  char* ws = (char*)d_ws;
  f16* xb = (f16*)ws;
  f16* wt = (f16*)(ws + (size_t)16 * 1024 * 1024);
  f16* q  = (f16*)(ws + (size_t)22 * 1024 * 1024);
  f16* kk = q + (size_t)BATCH * SEQ * D_MODEL;
  f16* vt = kk + (size_t)BATCH * SEQ * D_MODEL;

  prep_kernel<<<8192 + 768, 256, 0, stream>>>(x, Wq, Wk, Wv, xb, wt);
  qkv_gemm_kernel<<<1536, 256, 0, stream>>>(xb, wt, bq, bk, bv, q, kk, vt);
  attn_kernel<<<dim3(64, 16), 128, 0, stream>>>(q, kk, vt, out);
}